// Round 5
// baseline (1177.443 us; speedup 1.0000x reference)
//
#include <hip/hip_runtime.h>
#include <hip/hip_bf16.h>

#define HN 16
#define DM 1024
#define DK 64
#define BSZ 8
#define SEQL 1024

typedef __attribute__((ext_vector_type(8))) short bf16x8;
typedef __attribute__((ext_vector_type(4))) short short4v;
typedef __attribute__((ext_vector_type(4))) float f32x4;

// 0.125 * log2(e): folded into Wk/bk so attention uses native exp2
#define KSCALE 0.18033688011112042f

__device__ __forceinline__ short f2bf(float f) {
    union { float f; unsigned u; } x; x.f = f;
    unsigned u = x.u + 0x7FFFu + ((x.u >> 16) & 1u);
    return (short)(u >> 16);
}

// ---------------------------------------------------------------------------
// All 4 weight transposes in one dispatch; z selects weight. Wk scaled.
// ---------------------------------------------------------------------------
__global__ __launch_bounds__(256) void transpose_cast_all(
    const float* __restrict__ Wq, const float* __restrict__ Wk,
    const float* __restrict__ Wv, const float* __restrict__ Wo,
    short* __restrict__ Wqt, short* __restrict__ Wkt,
    short* __restrict__ Wvt, short* __restrict__ Wot) {
    const int z = blockIdx.z;
    const float* W = (z == 0) ? Wq : (z == 1) ? Wk : (z == 2) ? Wv : Wo;
    short* Wt = (z == 0) ? Wqt : (z == 1) ? Wkt : (z == 2) ? Wvt : Wot;
    const float scale = (z == 1) ? KSCALE : 1.0f;
    __shared__ float tile[32][33];
    const int t = threadIdx.x;
    const int k0 = blockIdx.x * 32, n0 = blockIdx.y * 32;
    const int c = t & 31, r = t >> 5;
    #pragma unroll
    for (int p = 0; p < 4; ++p)
        tile[r + 8 * p][c] = W[(size_t)(k0 + r + 8 * p) * DM + n0 + c];
    __syncthreads();
    #pragma unroll
    for (int p = 0; p < 4; ++p)
        Wt[(size_t)(n0 + r + 8 * p) * DM + k0 + c] = f2bf(tile[c][r + 8 * p] * scale);
}

// ---------------------------------------------------------------------------
// mask int32[8M] -> bits u64 (1 = keep), layout [z][q][j/64]
// ---------------------------------------------------------------------------
__global__ __launch_bounds__(256) void pack_mask(const int* __restrict__ mask,
                                                 unsigned long long* __restrict__ bits) {
    size_t i = (size_t)blockIdx.x * 256 + threadIdx.x;
    unsigned long long b = __ballot(mask[i] != 0);
    if ((threadIdx.x & 63) == 0) bits[i >> 6] = b;
}

// ---------------------------------------------------------------------------
// Fused QKV projection GEMM (one batch). blockIdx.z selects {Q,K,V}.
// 128x128 tile, BK=32, 4 waves, 4x4 frags. A fp32 row-major.
// which<2: C bf16 head-split [h][s][dk]; which==2: C bf16 [h][dk][s].
// ---------------------------------------------------------------------------
__global__ __launch_bounds__(256) void gemm_qkv(
    const float* __restrict__ Aq, const float* __restrict__ Ak,
    const float* __restrict__ Av,
    const short* __restrict__ Wqt, const short* __restrict__ Wkt,
    const short* __restrict__ Wvt,
    const float* __restrict__ bq, const float* __restrict__ bk,
    const float* __restrict__ bv,
    short* __restrict__ Qw, short* __restrict__ Kw, short* __restrict__ Vw) {
    const int which = blockIdx.z;
    const float* A = (which == 0) ? Aq : (which == 1) ? Ak : Av;
    const short* Wt = (which == 0) ? Wqt : (which == 1) ? Wkt : Wvt;
    const float* bias = (which == 0) ? bq : (which == 1) ? bk : bv;
    short* C = (which == 0) ? Qw : (which == 1) ? Kw : Vw;
    const float bsc = (which == 1) ? KSCALE : 1.0f;

    __shared__ __attribute__((aligned(16))) short As[128][40];
    __shared__ __attribute__((aligned(16))) short Bs[128][40];
    const int t = threadIdx.x;
    const int lane = t & 63, wv = t >> 6;
    const int wm = (wv >> 1) * 64, wn = (wv & 1) * 64;
    const int quad = lane >> 4, l15 = lane & 15;
    const int tileM = blockIdx.x * 128, tileN = blockIdx.y * 128;

    f32x4 acc[4][4];
    #pragma unroll
    for (int i = 0; i < 4; ++i)
        #pragma unroll
        for (int j = 0; j < 4; ++j) acc[i][j] = {0.f, 0.f, 0.f, 0.f};

    for (int k0 = 0; k0 < DM; k0 += 32) {
        {
            const int r0 = t >> 3, c4 = (t & 7) * 4;
            #pragma unroll
            for (int p = 0; p < 4; ++p) {
                int row = r0 + 32 * p;
                float4 v = *(const float4*)(A + (size_t)(tileM + row) * DM + k0 + c4);
                short4v s4 = {f2bf(v.x), f2bf(v.y), f2bf(v.z), f2bf(v.w)};
                *(short4v*)&As[row][c4] = s4;
            }
        }
        {
            const int r0 = t >> 2, c8 = (t & 3) * 8;
            #pragma unroll
            for (int p = 0; p < 2; ++p) {
                int row = r0 + 64 * p;
                *(bf16x8*)&Bs[row][c8] =
                    *(const bf16x8*)(Wt + (size_t)(tileN + row) * DM + k0 + c8);
            }
        }
        __syncthreads();
        bf16x8 a[4], b[4];
        #pragma unroll
        for (int i = 0; i < 4; ++i) a[i] = *(const bf16x8*)&As[wm + i * 16 + l15][quad * 8];
        #pragma unroll
        for (int j = 0; j < 4; ++j) b[j] = *(const bf16x8*)&Bs[wn + j * 16 + l15][quad * 8];
        #pragma unroll
        for (int i = 0; i < 4; ++i)
            #pragma unroll
            for (int j = 0; j < 4; ++j)
                acc[i][j] = __builtin_amdgcn_mfma_f32_16x16x32_bf16(a[i], b[j], acc[i][j], 0, 0, 0);
        __syncthreads();
    }

    #pragma unroll
    for (int i = 0; i < 4; ++i)
        #pragma unroll
        for (int j = 0; j < 4; ++j)
            #pragma unroll
            for (int rr = 0; rr < 4; ++rr) {
                int row = tileM + wm + i * 16 + quad * 4 + rr;
                int col = tileN + wn + j * 16 + l15;
                float v = acc[i][j][rr] + bias[col] * bsc;
                if (which < 2)
                    C[((size_t)(col >> 6) * SEQL + row) * DK + (col & 63)] = f2bf(v);
                else
                    C[(size_t)col * SEQL + row] = f2bf(v);  // [h][dk][s]
            }
}

// ---------------------------------------------------------------------------
// Output projection GEMM (one batch): A bf16 [s][dm] -> C fp32 [s][dm] (+bias)
// ---------------------------------------------------------------------------
__global__ __launch_bounds__(256) void gemm_out(const short* __restrict__ A,
                                                const short* __restrict__ Wt,
                                                const float* __restrict__ bias,
                                                float* __restrict__ C) {
    __shared__ __attribute__((aligned(16))) short As[128][40];
    __shared__ __attribute__((aligned(16))) short Bs[128][40];
    const int t = threadIdx.x;
    const int lane = t & 63, wv = t >> 6;
    const int wm = (wv >> 1) * 64, wn = (wv & 1) * 64;
    const int quad = lane >> 4, l15 = lane & 15;
    const int tileM = blockIdx.x * 128, tileN = blockIdx.y * 128;

    f32x4 acc[4][4];
    #pragma unroll
    for (int i = 0; i < 4; ++i)
        #pragma unroll
        for (int j = 0; j < 4; ++j) acc[i][j] = {0.f, 0.f, 0.f, 0.f};

    for (int k0 = 0; k0 < DM; k0 += 32) {
        const int r0 = t >> 2, c8 = (t & 3) * 8;
        #pragma unroll
        for (int p = 0; p < 2; ++p) {
            int row = r0 + 64 * p;
            *(bf16x8*)&As[row][c8] =
                *(const bf16x8*)(A + (size_t)(tileM + row) * DM + k0 + c8);
            *(bf16x8*)&Bs[row][c8] =
                *(const bf16x8*)(Wt + (size_t)(tileN + row) * DM + k0 + c8);
        }
        __syncthreads();
        bf16x8 a[4], b[4];
        #pragma unroll
        for (int i = 0; i < 4; ++i) a[i] = *(const bf16x8*)&As[wm + i * 16 + l15][quad * 8];
        #pragma unroll
        for (int j = 0; j < 4; ++j) b[j] = *(const bf16x8*)&Bs[wn + j * 16 + l15][quad * 8];
        #pragma unroll
        for (int i = 0; i < 4; ++i)
            #pragma unroll
            for (int j = 0; j < 4; ++j)
                acc[i][j] = __builtin_amdgcn_mfma_f32_16x16x32_bf16(a[i], b[j], acc[i][j], 0, 0, 0);
        __syncthreads();
    }

    #pragma unroll
    for (int i = 0; i < 4; ++i)
        #pragma unroll
        for (int j = 0; j < 4; ++j)
            #pragma unroll
            for (int rr = 0; rr < 4; ++rr) {
                int row = tileM + wm + i * 16 + quad * 4 + rr;
                int col = tileN + wn + j * 16 + l15;
                C[(size_t)row * DM + col] = acc[i][j][rr] + bias[col];
            }
}

// ---------------------------------------------------------------------------
// Attention v2 (one batch): block = 4 waves x 32 q-rows = 128 q, grid (8, 16).
// All MFMA fragments loaded directly from global (K/Q/V^T row-major = frag
// layout). Computes S^T = K.Q^T so P lands in LDS via vector ds_write_b64 and
// reads back as b128 A-frags. No __syncthreads anywhere. Kw pre-scaled by
// 0.125*log2e -> p = exp2(s) with native v_exp_f32.
// ---------------------------------------------------------------------------
__global__ __launch_bounds__(256) void attn_mfma2(
    const short* __restrict__ Qw, const short* __restrict__ Kw,
    const short* __restrict__ Vt, const unsigned long long* __restrict__ bits,
    short* __restrict__ ctx) {
    __shared__ __attribute__((aligned(16))) short Ps[4][32][72];
    __shared__ __attribute__((aligned(16))) float Ls[4][32];
    const int t = threadIdx.x;
    const int lane = t & 63, w = t >> 6;
    const int quad = lane >> 4, l15 = lane & 15;
    const int h = blockIdx.y;
    const int qbase = blockIdx.x * 128 + w * 32;
    const short* Qb = Qw + (size_t)h * SEQL * DK;
    const short* Kb = Kw + (size_t)h * SEQL * DK;
    const short* Vb = Vt + (size_t)h * DK * SEQL;

    // persistent Q B-frags: B[n=q][k=d]
    bf16x8 qf[2][2];
    #pragma unroll
    for (int qn = 0; qn < 2; ++qn)
        #pragma unroll
        for (int ks = 0; ks < 2; ++ks)
            qf[qn][ks] = *(const bf16x8*)(Qb + (size_t)(qbase + qn * 16 + l15) * DK +
                                          ks * 32 + quad * 8);

    f32x4 oc[2][4];
    #pragma unroll
    for (int qm = 0; qm < 2; ++qm)
        #pragma unroll
        for (int td = 0; td < 4; ++td) oc[qm][td] = {0.f, 0.f, 0.f, 0.f};
    float Lacc[2] = {0.f, 0.f};

    for (int j0 = 0; j0 < SEQL; j0 += 64) {
        // K A-frags: A[m=j][k=d]
        bf16x8 kf[4][2];
        #pragma unroll
        for (int jm = 0; jm < 4; ++jm)
            #pragma unroll
            for (int ks = 0; ks < 2; ++ks)
                kf[jm][ks] = *(const bf16x8*)(Kb + (size_t)(j0 + jm * 16 + l15) * DK +
                                              ks * 32 + quad * 8);
        // S^T[j][q]
        f32x4 st[4][2];
        #pragma unroll
        for (int jm = 0; jm < 4; ++jm)
            #pragma unroll
            for (int qn = 0; qn < 2; ++qn) {
                f32x4 s = {0.f, 0.f, 0.f, 0.f};
                s = __builtin_amdgcn_mfma_f32_16x16x32_bf16(kf[jm][0], qf[qn][0], s, 0, 0, 0);
                s = __builtin_amdgcn_mfma_f32_16x16x32_bf16(kf[jm][1], qf[qn][1], s, 0, 0, 0);
                st[jm][qn] = s;
            }
        unsigned long long mw[2];
        #pragma unroll
        for (int qn = 0; qn < 2; ++qn)
            mw[qn] = bits[(size_t)(qbase + qn * 16 + l15) * 16 + (j0 >> 6)];

        // p = keep ? exp2(s) : 0 ; write b64 into Ps[q][j]
        #pragma unroll
        for (int jm = 0; jm < 4; ++jm)
            #pragma unroll
            for (int qn = 0; qn < 2; ++qn) {
                short4v p4;
                #pragma unroll
                for (int rr = 0; rr < 4; ++rr) {
                    bool keep = (mw[qn] >> (jm * 16 + quad * 4 + rr)) & 1ull;
                    float e = exp2f(keep ? st[jm][qn][rr] : -1e30f);
                    Lacc[qn] += e;
                    p4[rr] = f2bf(e);
                }
                *(short4v*)&Ps[w][qn * 16 + l15][jm * 16 + quad * 4] = p4;
            }

        // O += P.V : A[m=q][k=j] from Ps, B[n=d][k=j] from V^T (global)
        #pragma unroll
        for (int ks = 0; ks < 2; ++ks) {
            bf16x8 pf[2];
            #pragma unroll
            for (int qm = 0; qm < 2; ++qm)
                pf[qm] = *(const bf16x8*)&Ps[w][qm * 16 + l15][ks * 32 + quad * 8];
            #pragma unroll
            for (int td = 0; td < 4; ++td) {
                bf16x8 vf = *(const bf16x8*)(Vb + (size_t)(td * 16 + l15) * SEQL + j0 +
                                             ks * 32 + quad * 8);
                oc[0][td] = __builtin_amdgcn_mfma_f32_16x16x32_bf16(pf[0], vf, oc[0][td], 0, 0, 0);
                oc[1][td] = __builtin_amdgcn_mfma_f32_16x16x32_bf16(pf[1], vf, oc[1][td], 0, 0, 0);
            }
        }
    }

    // L: reduce across quads (lanes l15, l15+16, +32, +48 share q)
    #pragma unroll
    for (int qn = 0; qn < 2; ++qn) {
        float l = Lacc[qn];
        l += __shfl_xor(l, 16);
        l += __shfl_xor(l, 32);
        Ls[w][qn * 16 + l15] = 1.0f / l;  // all quads write identical value
    }
    f32x4 rv[2];
    #pragma unroll
    for (int qm = 0; qm < 2; ++qm) rv[qm] = *(f32x4*)&Ls[w][qm * 16 + quad * 4];

    #pragma unroll
    for (int qm = 0; qm < 2; ++qm)
        #pragma unroll
        for (int td = 0; td < 4; ++td)
            #pragma unroll
            for (int rr = 0; rr < 4; ++rr) {
                int rq = qbase + qm * 16 + quad * 4 + rr;
                int cd = h * 64 + td * 16 + l15;
                ctx[(size_t)rq * DM + cd] = f2bf(oc[qm][td][rr] * rv[qm][rr]);
            }
}

extern "C" void kernel_launch(void* const* d_in, const int* in_sizes, int n_in,
                              void* d_out, int out_size, void* d_ws, size_t ws_size,
                              hipStream_t stream) {
    const float* q  = (const float*)d_in[0];
    const float* k  = (const float*)d_in[1];
    const float* v  = (const float*)d_in[2];
    const int* mask = (const int*)d_in[3];
    const float* Wq = (const float*)d_in[4];
    const float* bq = (const float*)d_in[5];
    const float* Wk = (const float*)d_in[6];
    const float* bk = (const float*)d_in[7];
    const float* Wv = (const float*)d_in[8];
    const float* bv = (const float*)d_in[9];
    const float* Wo = (const float*)d_in[10];
    const float* bo = (const float*)d_in[11];
    float* out = (float*)d_out;

    const size_t MB = (size_t)1 << 20;
    const size_t MEL = (size_t)1024 * 1024;
    char* base = (char*)d_ws;

    // ws (16 MB): 4 transposed weights (8 MB) + per-batch Qw/Kw/Vw/ctx (8 MB)
    short* Wqt = (short*)(base + 0 * 2 * MB);
    short* Wkt = (short*)(base + 1 * 2 * MB);
    short* Wvt = (short*)(base + 2 * 2 * MB);
    short* Wot = (short*)(base + 3 * 2 * MB);
    short* Qw  = (short*)(base + 8 * MB);
    short* Kw  = (short*)(base + 10 * MB);
    short* Vw  = (short*)(base + 12 * MB);
    short* ctx = (short*)(base + 14 * MB);

    // mask bits (1 MB) live in d_out's batch-7 region (out+28MB..29MB):
    // consumed by every attn dispatch (last consumer: batch-7 attn), then
    // overwritten by batch-7's gemm_out. d_out fully rewritten every call.
    unsigned long long* bits = (unsigned long long*)((char*)d_out + 28 * MB);

    transpose_cast_all<<<dim3(32, 32, 4), 256, 0, stream>>>(Wq, Wk, Wv, Wo,
                                                            Wqt, Wkt, Wvt, Wot);
    pack_mask<<<(BSZ * SEQL * SEQL) / 256, 256, 0, stream>>>(mask, bits);

    for (int it = 0; it < BSZ; ++it) {
        const size_t boff = (size_t)it * MEL;
        gemm_qkv<<<dim3(8, 8, 3), 256, 0, stream>>>(q + boff, k + boff, v + boff,
                                                    Wqt, Wkt, Wvt, bq, bk, bv,
                                                    Qw, Kw, Vw);
        attn_mfma2<<<dim3(8, HN), 256, 0, stream>>>(Qw, Kw, Vw,
                                                    bits + (size_t)it * SEQL * 16, ctx);
        gemm_out<<<dim3(8, 8), 256, 0, stream>>>(ctx, Wot, bo, out + boff);
    }
}